// Round 1
// baseline (2261.788 us; speedup 1.0000x reference)
//
#include <hip/hip_runtime.h>
#include <cstddef>

#define BDIM 4
#define CH   256
#define HD   128
#define NP   4096
#define SS   16
#define PADS 20   // padded row stride for [HD][S] LDS tiles: 80B, 16B-aligned, 8-bank spread

// ---------------------------------------------------------------------------
// Kernel 1: xc = W_top @ x_centroids + b_top ; phi = W_phi @ xc + b_phi
// One block = 16 points (amortizes weight reads). phi_ws layout: [pt][h].
// ---------------------------------------------------------------------------
__global__ __launch_bounds__(256) void k_phi(
    const float* __restrict__ xcent,
    const float* __restrict__ Wtop, const float* __restrict__ btop,
    const float* __restrict__ Wphi, const float* __restrict__ bphi,
    float* __restrict__ phi_ws)
{
    __shared__ float xcs[CH][SS];   // 16 KB
    __shared__ float xc2[HD][SS];   //  8 KB
    const int blk = blockIdx.x;     // 0..1023
    const int b   = blk >> 8;
    const int n0  = (blk & 255) * SS;
    const int t   = threadIdx.x;

    {   // stage x_centroids tile: row c=t, 16 consecutive n (64B contiguous)
        const float* src = xcent + ((size_t)(b*CH + t))*NP + n0;
        *(float4*)&xcs[t][0]  = *(const float4*)(src);
        *(float4*)&xcs[t][4]  = *(const float4*)(src + 4);
        *(float4*)&xcs[t][8]  = *(const float4*)(src + 8);
        *(float4*)&xcs[t][12] = *(const float4*)(src + 12);
    }
    __syncthreads();

    const int h  = t & 127;
    const int p0 = (t >> 7) * 8;     // this thread handles 8 of the 16 points

    {   // xc = W_top @ x + b_top
        float acc[8];
        const float bb = btop[h];
#pragma unroll
        for (int j = 0; j < 8; ++j) acc[j] = bb;
        const float* wr = Wtop + h*CH;
        for (int c4 = 0; c4 < CH/4; ++c4) {
            const float4 w4 = *(const float4*)&wr[c4*4];
            const float wv[4] = {w4.x, w4.y, w4.z, w4.w};
#pragma unroll
            for (int u = 0; u < 4; ++u) {
                const int c = c4*4 + u;
                float xr[8];
                *(float4*)&xr[0] = *(const float4*)&xcs[c][p0];
                *(float4*)&xr[4] = *(const float4*)&xcs[c][p0+4];
#pragma unroll
                for (int j = 0; j < 8; ++j) acc[j] += wv[u]*xr[j];
            }
        }
#pragma unroll
        for (int j = 0; j < 8; ++j) xc2[h][p0+j] = acc[j];
    }
    __syncthreads();
    {   // phi = W_phi @ xc + b_phi
        float acc[8];
        const float bb = bphi[h];
#pragma unroll
        for (int j = 0; j < 8; ++j) acc[j] = bb;
        const float* wr = Wphi + h*HD;
        for (int k4 = 0; k4 < HD/4; ++k4) {
            const float4 w4 = *(const float4*)&wr[k4*4];
            const float wv[4] = {w4.x, w4.y, w4.z, w4.w};
#pragma unroll
            for (int u = 0; u < 4; ++u) {
                const int k = k4*4 + u;
                float xr[8];
                *(float4*)&xr[0] = *(const float4*)&xc2[k][p0];
                *(float4*)&xr[4] = *(const float4*)&xc2[k][p0+4];
#pragma unroll
                for (int j = 0; j < 8; ++j) acc[j] += wv[u]*xr[j];
            }
        }
        const size_t base = ((size_t)(b*NP + n0))*HD;
#pragma unroll
        for (int j = 0; j < 8; ++j) phi_ws[base + (size_t)(p0+j)*HD + h] = acc[j];
    }
}

// ---------------------------------------------------------------------------
// Kernel 2: fused per-point pipeline.
// delta -> psi/alpha (c-chunked x staging) -> gamma MLP -> softmax -> y
// One block (256 thr) per point. Thread t = (h = t&127, s-half = t>>7).
// ---------------------------------------------------------------------------
__global__ __launch_bounds__(256) void k_main(
    const float* __restrict__ pcent, const float* __restrict__ pfull,
    const float* __restrict__ xfull,
    const float* __restrict__ Wpsi,   const float* __restrict__ bpsi,
    const float* __restrict__ Walpha, const float* __restrict__ balpha,
    const float* __restrict__ Wg1,    const float* __restrict__ bg1,
    const float* __restrict__ Wg2,    const float* __restrict__ bg2,
    const float* __restrict__ Wd1,    const float* __restrict__ bd1,
    const float* __restrict__ Wd2,    const float* __restrict__ bd2,
    const float* __restrict__ phi_ws, float* __restrict__ y_ws)
{
    __shared__ float xchunk[64][SS];    // 4 KB  (c-chunk x tile)
    __shared__ float d1g1[HD][PADS];    // 10 KB (d1, later g1)
    __shared__ float dlt[HD][PADS];     // 10 KB (delta_p)
    __shared__ float gin[HD][PADS];     // 10 KB (gamma input, later g)
    __shared__ float av[HD][PADS];      // 10 KB (alpha + delta)
    __shared__ float pipj[3][SS];
    __shared__ float phis[HD];

    const int pt = blockIdx.x;
    const int b  = pt >> 12;
    const int n  = pt & (NP - 1);
    const int t  = threadIdx.x;
    const int h  = t & 127;
    const int sh = t >> 7;
    const int s0 = sh * 8;

    if (t < 48) {
        const int k = t >> 4, s = t & 15;
        const size_t ip = ((size_t)(b*3 + k))*NP + n;
        pipj[k][s] = pcent[ip] - pfull[ip*SS + s];
    }
    if (t < HD) phis[t] = phi_ws[(size_t)pt*HD + t];
    __syncthreads();

    // ---- d1 = relu(W_d1 @ pipj + b_d1) ----
    {
        const float w0 = Wd1[h*3], w1 = Wd1[h*3+1], w2 = Wd1[h*3+2];
        const float bb = bd1[h];
#pragma unroll
        for (int j = 0; j < 8; ++j) {
            const int s = s0 + j;
            d1g1[h][s] = fmaxf(bb + w0*pipj[0][s] + w1*pipj[1][s] + w2*pipj[2][s], 0.f);
        }
    }
    __syncthreads();

    // ---- delta = W_d2 @ d1 + b_d2 ----
    {
        float acc[8];
        const float bb = bd2[h];
#pragma unroll
        for (int j = 0; j < 8; ++j) acc[j] = bb;
        const float* wr = Wd2 + h*HD;
        for (int k4 = 0; k4 < HD/4; ++k4) {
            const float4 w4 = *(const float4*)&wr[k4*4];
            const float wv[4] = {w4.x, w4.y, w4.z, w4.w};
#pragma unroll
            for (int u = 0; u < 4; ++u) {
                const int k = k4*4 + u;
                float xr[8];
                *(float4*)&xr[0] = *(const float4*)&d1g1[k][s0];
                *(float4*)&xr[4] = *(const float4*)&d1g1[k][s0+4];
#pragma unroll
                for (int j = 0; j < 8; ++j) acc[j] += wv[u]*xr[j];
            }
        }
#pragma unroll
        for (int j = 0; j < 8; ++j) dlt[h][s0+j] = acc[j];
    }
    __syncthreads();

    // ---- psi & alpha over c-chunks of 64 (each thread: both rows, 8 s) ----
    {
        float accp[8], acca[8];
        {
            const float bp = bpsi[h], ba = balpha[h];
#pragma unroll
            for (int j = 0; j < 8; ++j) { accp[j] = bp; acca[j] = ba; }
        }
        const float* wp = Wpsi   + h*CH;
        const float* wa = Walpha + h*CH;
        for (int ch = 0; ch < 4; ++ch) {
            if (ch) __syncthreads();
            {   // stage 64x16 x-tile: thread t loads one float4
                const int ci  = t >> 2;
                const int ss2 = (t & 3) * 4;
                const float4 v = *(const float4*)&xfull[(((size_t)(b*CH + ch*64 + ci))*NP + n)*SS + ss2];
                *(float4*)&xchunk[ci][ss2] = v;
            }
            __syncthreads();
            const int cb = ch*64;
            for (int c4 = 0; c4 < 16; ++c4) {
                const float4 wp4 = *(const float4*)&wp[cb + c4*4];
                const float4 wa4 = *(const float4*)&wa[cb + c4*4];
                const float wpv[4] = {wp4.x, wp4.y, wp4.z, wp4.w};
                const float wav[4] = {wa4.x, wa4.y, wa4.z, wa4.w};
#pragma unroll
                for (int u = 0; u < 4; ++u) {
                    const int ci = c4*4 + u;
                    float xr[8];
                    *(float4*)&xr[0] = *(const float4*)&xchunk[ci][s0];
                    *(float4*)&xr[4] = *(const float4*)&xchunk[ci][s0+4];
#pragma unroll
                    for (int j = 0; j < 8; ++j) {
                        accp[j] += wpv[u]*xr[j];
                        acca[j] += wav[u]*xr[j];
                    }
                }
            }
        }
        const float ph = phis[h];
#pragma unroll
        for (int j = 0; j < 8; ++j) {
            const int s = s0 + j;
            const float d = dlt[h][s];
            gin[h][s] = ph - accp[j] + d;
            av [h][s] = acca[j] + d;
        }
    }
    __syncthreads();

    // ---- g1 = relu(W_g1 @ gin + b_g1) -> d1g1 ----
    {
        float acc[8];
        const float bb = bg1[h];
#pragma unroll
        for (int j = 0; j < 8; ++j) acc[j] = bb;
        const float* wr = Wg1 + h*HD;
        for (int k4 = 0; k4 < HD/4; ++k4) {
            const float4 w4 = *(const float4*)&wr[k4*4];
            const float wv[4] = {w4.x, w4.y, w4.z, w4.w};
#pragma unroll
            for (int u = 0; u < 4; ++u) {
                const int k = k4*4 + u;
                float xr[8];
                *(float4*)&xr[0] = *(const float4*)&gin[k][s0];
                *(float4*)&xr[4] = *(const float4*)&gin[k][s0+4];
#pragma unroll
                for (int j = 0; j < 8; ++j) acc[j] += wv[u]*xr[j];
            }
        }
#pragma unroll
        for (int j = 0; j < 8; ++j) d1g1[h][s0+j] = fmaxf(acc[j], 0.f);
    }
    __syncthreads();

    // ---- g = W_g2 @ g1 + b_g2 -> gin (reuse) ----
    {
        float acc[8];
        const float bb = bg2[h];
#pragma unroll
        for (int j = 0; j < 8; ++j) acc[j] = bb;
        const float* wr = Wg2 + h*HD;
        for (int k4 = 0; k4 < HD/4; ++k4) {
            const float4 w4 = *(const float4*)&wr[k4*4];
            const float wv[4] = {w4.x, w4.y, w4.z, w4.w};
#pragma unroll
            for (int u = 0; u < 4; ++u) {
                const int k = k4*4 + u;
                float xr[8];
                *(float4*)&xr[0] = *(const float4*)&d1g1[k][s0];
                *(float4*)&xr[4] = *(const float4*)&d1g1[k][s0+4];
#pragma unroll
                for (int j = 0; j < 8; ++j) acc[j] += wv[u]*xr[j];
            }
        }
#pragma unroll
        for (int j = 0; j < 8; ++j) gin[h][s0+j] = acc[j];
    }
    __syncthreads();

    // ---- softmax over s + weighted sum -> y_ws[pt][h] ----
    if (t < HD) {
        float gv[SS], avv[SS];
        *(float4*)&gv[0]   = *(const float4*)&gin[t][0];
        *(float4*)&gv[4]   = *(const float4*)&gin[t][4];
        *(float4*)&gv[8]   = *(const float4*)&gin[t][8];
        *(float4*)&gv[12]  = *(const float4*)&gin[t][12];
        *(float4*)&avv[0]  = *(const float4*)&av[t][0];
        *(float4*)&avv[4]  = *(const float4*)&av[t][4];
        *(float4*)&avv[8]  = *(const float4*)&av[t][8];
        *(float4*)&avv[12] = *(const float4*)&av[t][12];
        float m = gv[0];
#pragma unroll
        for (int s = 1; s < SS; ++s) m = fmaxf(m, gv[s]);
        float sum = 0.f, acc = 0.f;
#pragma unroll
        for (int s = 0; s < SS; ++s) {
            const float e = expf(gv[s] - m);
            sum += e;
            acc += e * avv[s];
        }
        y_ws[(size_t)pt*HD + t] = acc / sum;
    }
}

// ---------------------------------------------------------------------------
// Kernel 3: out = W_down @ y + b_down + x_centroids (residual)
// One block = 16 points; thread t = output channel c.
// ---------------------------------------------------------------------------
__global__ __launch_bounds__(256) void k_down(
    const float* __restrict__ y_ws,
    const float* __restrict__ Wdown, const float* __restrict__ bdown,
    const float* __restrict__ xcent, float* __restrict__ out)
{
    __shared__ float yls[HD][SS];   // 8 KB
    const int blk = blockIdx.x;
    const int b   = blk >> 8;
    const int n0  = (blk & 255) * SS;
    const int t   = threadIdx.x;

    {   // stage y tile: flat f = p*HD + h
        const float* src = y_ws + ((size_t)(b*NP + n0))*HD;
        float v[8];
        *(float4*)&v[0] = *(const float4*)(src + t*8);
        *(float4*)&v[4] = *(const float4*)(src + t*8 + 4);
#pragma unroll
        for (int j = 0; j < 8; ++j) {
            const int f = t*8 + j;
            yls[f & 127][f >> 7] = v[j];
        }
    }
    __syncthreads();

    const int c = t;
    float acc[SS];
    {
        const float bb = bdown[c];
#pragma unroll
        for (int p = 0; p < SS; ++p) acc[p] = bb;
    }
    const float* wr = Wdown + c*HD;
    for (int k4 = 0; k4 < HD/4; ++k4) {
        const float4 w4 = *(const float4*)&wr[k4*4];
        const float wv[4] = {w4.x, w4.y, w4.z, w4.w};
#pragma unroll
        for (int u = 0; u < 4; ++u) {
            const int k = k4*4 + u;
            float yr[SS];
            *(float4*)&yr[0]  = *(const float4*)&yls[k][0];
            *(float4*)&yr[4]  = *(const float4*)&yls[k][4];
            *(float4*)&yr[8]  = *(const float4*)&yls[k][8];
            *(float4*)&yr[12] = *(const float4*)&yls[k][12];
#pragma unroll
            for (int p = 0; p < SS; ++p) acc[p] += wv[u]*yr[p];
        }
    }
    const size_t ob = ((size_t)(b*CH + c))*NP + n0;
#pragma unroll
    for (int p4 = 0; p4 < 4; ++p4) {
        const float4 r = *(const float4*)&xcent[ob + p4*4];
        float4 o;
        o.x = acc[p4*4+0] + r.x;
        o.y = acc[p4*4+1] + r.y;
        o.z = acc[p4*4+2] + r.z;
        o.w = acc[p4*4+3] + r.w;
        *(float4*)&out[ob + p4*4] = o;
    }
}

// ---------------------------------------------------------------------------
extern "C" void kernel_launch(void* const* d_in, const int* in_sizes, int n_in,
                              void* d_out, int out_size, void* d_ws, size_t ws_size,
                              hipStream_t stream)
{
    const float* pcent  = (const float*)d_in[0];
    const float* xcent  = (const float*)d_in[1];
    const float* pfull  = (const float*)d_in[2];
    const float* xfull  = (const float*)d_in[3];
    const float* Wtop   = (const float*)d_in[4];
    const float* btop   = (const float*)d_in[5];
    const float* Wdown  = (const float*)d_in[6];
    const float* bdown  = (const float*)d_in[7];
    const float* Wphi   = (const float*)d_in[8];
    const float* bphi   = (const float*)d_in[9];
    const float* Wpsi   = (const float*)d_in[10];
    const float* bpsi   = (const float*)d_in[11];
    const float* Walpha = (const float*)d_in[12];
    const float* balpha = (const float*)d_in[13];
    const float* Wg1    = (const float*)d_in[14];
    const float* bg1    = (const float*)d_in[15];
    const float* Wg2    = (const float*)d_in[16];
    const float* bg2    = (const float*)d_in[17];
    const float* Wd1    = (const float*)d_in[18];
    const float* bd1    = (const float*)d_in[19];
    const float* Wd2    = (const float*)d_in[20];
    const float* bd2    = (const float*)d_in[21];
    float* out = (float*)d_out;

    float* phi_ws = (float*)d_ws;                        // B*N*H floats = 8.4 MB
    float* y_ws   = phi_ws + (size_t)BDIM*NP*HD;         // B*N*H floats = 8.4 MB

    k_phi <<<BDIM*NP/SS, 256, 0, stream>>>(xcent, Wtop, btop, Wphi, bphi, phi_ws);
    k_main<<<BDIM*NP,    256, 0, stream>>>(pcent, pfull, xfull,
                                           Wpsi, bpsi, Walpha, balpha,
                                           Wg1, bg1, Wg2, bg2,
                                           Wd1, bd1, Wd2, bd2,
                                           phi_ws, y_ws);
    k_down<<<BDIM*NP/SS, 256, 0, stream>>>(y_ws, Wdown, bdown, xcent, out);
}

// Round 2
// 691.195 us; speedup vs baseline: 3.2723x; 3.2723x over previous
//
#include <hip/hip_runtime.h>
#include <cstddef>

#define BDIM 4
#define CH   256
#define HD   128
#define NP   4096
#define SS   16
#define PB   8      // points per k_main block
#define NCOL 128    // PB*SS GEMM columns

typedef __attribute__((ext_vector_type(8))) short short8v;
typedef __attribute__((ext_vector_type(4))) short short4v;
typedef __attribute__((ext_vector_type(4))) float f32x4;

// XOR swizzle (bit 4) on byte offsets within a K-contiguous row: spreads the
// 16B slots of 8 neighboring cols across banks; preserved by b64/b128 ops.
#define SWZ(col, off) ((off) ^ (((col)&7)<<4))

__device__ __forceinline__ unsigned short f2bf(float f){
  union { float f; unsigned u; } v; v.f = f;
  return (unsigned short)((v.u + 0x7fffu + ((v.u>>16)&1u)) >> 16);  // RNE
}
__device__ __forceinline__ f32x4 mm(short8v a, short8v b, f32x4 c){
  return __builtin_amdgcn_mfma_f32_16x16x32_bf16(a, b, c, 0, 0, 0);
}

// ---------------------------------------------------------------------------
// fp32 -> bf16 weight conversion (prep)
// ---------------------------------------------------------------------------
__global__ void k_cvt(const float* __restrict__ src, short* __restrict__ dst, int n){
  int i = blockIdx.x*256 + threadIdx.x;
  if (i < n) dst[i] = (short)f2bf(src[i]);
}

// ---------------------------------------------------------------------------
// Kernel 1 (unchanged fp32): xc = W_top@xc + b ; phi = W_phi@xc + b
// ---------------------------------------------------------------------------
__global__ __launch_bounds__(256) void k_phi(
    const float* __restrict__ xcent,
    const float* __restrict__ Wtop, const float* __restrict__ btop,
    const float* __restrict__ Wphi, const float* __restrict__ bphi,
    float* __restrict__ phi_ws)
{
    __shared__ float xcs[CH][SS];
    __shared__ float xc2[HD][SS];
    const int blk = blockIdx.x;
    const int b   = blk >> 8;
    const int n0  = (blk & 255) * SS;
    const int t   = threadIdx.x;

    {
        const float* src = xcent + ((size_t)(b*CH + t))*NP + n0;
        *(float4*)&xcs[t][0]  = *(const float4*)(src);
        *(float4*)&xcs[t][4]  = *(const float4*)(src + 4);
        *(float4*)&xcs[t][8]  = *(const float4*)(src + 8);
        *(float4*)&xcs[t][12] = *(const float4*)(src + 12);
    }
    __syncthreads();

    const int h  = t & 127;
    const int p0 = (t >> 7) * 8;

    {
        float acc[8];
        const float bb = btop[h];
#pragma unroll
        for (int j = 0; j < 8; ++j) acc[j] = bb;
        const float* wr = Wtop + h*CH;
        for (int c4 = 0; c4 < CH/4; ++c4) {
            const float4 w4 = *(const float4*)&wr[c4*4];
            const float wv[4] = {w4.x, w4.y, w4.z, w4.w};
#pragma unroll
            for (int u = 0; u < 4; ++u) {
                const int c = c4*4 + u;
                float xr[8];
                *(float4*)&xr[0] = *(const float4*)&xcs[c][p0];
                *(float4*)&xr[4] = *(const float4*)&xcs[c][p0+4];
#pragma unroll
                for (int j = 0; j < 8; ++j) acc[j] += wv[u]*xr[j];
            }
        }
#pragma unroll
        for (int j = 0; j < 8; ++j) xc2[h][p0+j] = acc[j];
    }
    __syncthreads();
    {
        float acc[8];
        const float bb = bphi[h];
#pragma unroll
        for (int j = 0; j < 8; ++j) acc[j] = bb;
        const float* wr = Wphi + h*HD;
        for (int k4 = 0; k4 < HD/4; ++k4) {
            const float4 w4 = *(const float4*)&wr[k4*4];
            const float wv[4] = {w4.x, w4.y, w4.z, w4.w};
#pragma unroll
            for (int u = 0; u < 4; ++u) {
                const int k = k4*4 + u;
                float xr[8];
                *(float4*)&xr[0] = *(const float4*)&xc2[k][p0];
                *(float4*)&xr[4] = *(const float4*)&xc2[k][p0+4];
#pragma unroll
                for (int j = 0; j < 8; ++j) acc[j] += wv[u]*xr[j];
            }
        }
        const size_t base = ((size_t)(b*NP + n0))*HD;
#pragma unroll
        for (int j = 0; j < 8; ++j) phi_ws[base + (size_t)(p0+j)*HD + h] = acc[j];
    }
}

// ---------------------------------------------------------------------------
// Kernel 2: MFMA pipeline. Block = 8 points (128 cols), 512 thr (8 waves).
// Wave grid: 4 row-groups x 2 col-groups; wave tile = 32 rows x 64 cols.
// Frag mapping (16x16x32): A lane: row=l&15, k=(l>>4)*8+i (contig 8);
// B lane: col=l&15, k=(l>>4)*8+i;  C/D lane: col=l&15, row=(l>>4)*4+j.
// Activations in LDS as [col][k] bf16 (K-contig), XOR-bit4 swizzled.
// ---------------------------------------------------------------------------
__global__ __launch_bounds__(512) void k_main_mfma(
    const float* __restrict__ pcent, const float* __restrict__ pfull,
    const float* __restrict__ xfull,
    const short* __restrict__ Wpsi_bf,   const float* __restrict__ bpsi,
    const short* __restrict__ Walpha_bf, const float* __restrict__ balpha,
    const short* __restrict__ Wd2_bf,    const float* __restrict__ bd2,
    const short* __restrict__ Wg1_bf,    const float* __restrict__ bg1,
    const short* __restrict__ Wg2_bf,    const float* __restrict__ bg2,
    const float* __restrict__ Wd1,       const float* __restrict__ bd1,
    const float* __restrict__ phi_ws,    float* __restrict__ y_ws)
{
  // bufA: d1T then ginT   [128 col][128 k] bf16, row stride 256B
  // bufB: x chunks (2x16KB, [128 col][64 k], stride 128B) then g1T (stride 256B)
  __shared__ __align__(16) char bufA[32768];
  __shared__ __align__(16) char bufB[32768];
  __shared__ __align__(16) float pipj[3][NCOL];
  __shared__ __align__(16) float phis[PB*HD];

  const int blk = blockIdx.x;
  const int b   = blk >> 9;           // 512 blocks per batch
  const int n0  = (blk & 511) * PB;
  const int t   = threadIdx.x;
  const int w   = t >> 6;             // wave 0..7
  const int lane= t & 63;
  const int rg  = w & 3;              // rows rg*32 .. +31
  const int cg  = w >> 2;             // cols cg*64 .. +63
  const int l15 = lane & 15;
  const int kg  = lane >> 4;

  // ---- stage pipj + phi tile ----
  if (t < 3*NCOL) {
    const int m = t >> 7, col = t & 127;
    pipj[m][col] = pcent[((size_t)(b*3+m))*NP + n0 + (col>>4)]
                 - pfull[(((size_t)(b*3+m))*NP + n0)*SS + col];
  }
  phis[t]       = phi_ws[((size_t)(b*NP) + n0)*HD + t];
  phis[t + 512] = phi_ws[((size_t)(b*NP) + n0)*HD + t + 512];
  __syncthreads();

  // ---- d1 = relu(Wd1 @ pipj + bd1) -> bufA[col][h] bf16 ----
  {
    const int col = t & 127;
    const int hq  = t >> 7;           // 4 groups x 32 h
    const float p0 = pipj[0][col], p1 = pipj[1][col], p2 = pipj[2][col];
#pragma unroll
    for (int i = 0; i < 4; ++i) {
      const int h0 = hq*32 + i*8;
      short8v pk;
#pragma unroll
      for (int j = 0; j < 8; ++j) {
        const int h = h0 + j;
        float v = bd1[h] + Wd1[h*3]*p0 + Wd1[h*3+1]*p1 + Wd1[h*3+2]*p2;
        pk[j] = (short)f2bf(fmaxf(v, 0.f));
      }
      *(short8v*)(bufA + col*256 + SWZ(col, h0*2)) = pk;
    }
  }
  __syncthreads();

  // ---- x chunk staging helpers (reg-staged, issue-early / write-late) ----
  float xl[16];
  const float* xsrc = xfull + (((size_t)(b*CH))*NP + n0)*SS;
#define XLOAD(cc) {                                                        \
  _Pragma("unroll") for (int p = 0; p < 2; ++p)                            \
  _Pragma("unroll") for (int j = 0; j < 8; ++j)                            \
    xl[p*8+j] = xsrc[((size_t)((cc)*64 + w*8 + j))*(NP*SS) + p*64 + lane]; }
#define XWRITE(cc) {                                                       \
  char* cb = bufB + ((cc)&1)*16384;                                        \
  _Pragma("unroll") for (int p = 0; p < 2; ++p) {                          \
    short8v pk;                                                            \
    _Pragma("unroll") for (int j = 0; j < 8; ++j)                          \
      pk[j] = (short)f2bf(xl[p*8+j]);                                      \
    const int col = p*64 + lane;                                           \
    *(short8v*)(cb + col*128 + SWZ(col, w*16)) = pk; } }

  // ---- delta GEMM (A=Wd2, B=d1T, K=128), chunk0 loads in flight ----
  f32x4 dacc[2][4];
#pragma unroll
  for (int rt = 0; rt < 2; ++rt) {
    const int r0 = rg*32 + rt*16 + kg*4;
    f32x4 bv = *(const f32x4*)(bd2 + r0);
#pragma unroll
    for (int ct = 0; ct < 4; ++ct) dacc[rt][ct] = bv;
  }
  XLOAD(0);
#pragma unroll
  for (int ks = 0; ks < 4; ++ks) {
    short8v a0 = *(const short8v*)(Wd2_bf + (rg*32 +      l15)*HD + ks*32 + kg*8);
    short8v a1 = *(const short8v*)(Wd2_bf + (rg*32 + 16 + l15)*HD + ks*32 + kg*8);
#pragma unroll
    for (int ct = 0; ct < 4; ++ct) {
      const int col = cg*64 + ct*16 + l15;
      short8v bf = *(const short8v*)(bufA + col*256 + SWZ(col, (ks*32+kg*8)*2));
      dacc[0][ct] = mm(a0, bf, dacc[0][ct]);
      dacc[1][ct] = mm(a1, bf, dacc[1][ct]);
    }
  }
  XWRITE(0);
  __syncthreads();

  // ---- psi & alpha GEMMs over 4 x-chunks (K=256), double-buffered ----
  f32x4 pacc[2][4], aacc[2][4];
#pragma unroll
  for (int rt = 0; rt < 2; ++rt) {
    const int r0 = rg*32 + rt*16 + kg*4;
    f32x4 bp = *(const f32x4*)(bpsi + r0);
    f32x4 ba = *(const f32x4*)(balpha + r0);
#pragma unroll
    for (int ct = 0; ct < 4; ++ct) { pacc[rt][ct] = bp; aacc[rt][ct] = ba; }
  }
#pragma unroll
  for (int cc = 0; cc < 4; ++cc) {
    if (cc < 3) XLOAD(cc+1);
    const char* cb = bufB + (cc&1)*16384;
#pragma unroll
    for (int ks = 0; ks < 2; ++ks) {
      const int k0 = cc*64 + ks*32;
      short8v ap0 = *(const short8v*)(Wpsi_bf   + (rg*32 +      l15)*CH + k0 + kg*8);
      short8v ap1 = *(const short8v*)(Wpsi_bf   + (rg*32 + 16 + l15)*CH + k0 + kg*8);
      short8v aa0 = *(const short8v*)(Walpha_bf + (rg*32 +      l15)*CH + k0 + kg*8);
      short8v aa1 = *(const short8v*)(Walpha_bf + (rg*32 + 16 + l15)*CH + k0 + kg*8);
#pragma unroll
      for (int ct = 0; ct < 4; ++ct) {
        const int col = cg*64 + ct*16 + l15;
        short8v bf = *(const short8v*)(cb + col*128 + SWZ(col, (ks*32+kg*8)*2));
        pacc[0][ct] = mm(ap0, bf, pacc[0][ct]);
        pacc[1][ct] = mm(ap1, bf, pacc[1][ct]);
        aacc[0][ct] = mm(aa0, bf, aacc[0][ct]);
        aacc[1][ct] = mm(aa1, bf, aacc[1][ct]);
      }
    }
    if (cc < 3) XWRITE(cc+1);
    __syncthreads();
  }

  // ---- gin = phi - psi + delta -> bufA ; av = alpha + delta (regs) ----
  f32x4 avv[2][4];
#pragma unroll
  for (int rt = 0; rt < 2; ++rt) {
    const int r0 = rg*32 + rt*16 + kg*4;
#pragma unroll
    for (int ct = 0; ct < 4; ++ct) {
      const int col = cg*64 + ct*16 + l15;
      const int p   = (cg*64 + ct*16) >> 4;
      f32x4 ph = *(const f32x4*)(phis + p*HD + r0);
      f32x4 g  = ph - pacc[rt][ct] + dacc[rt][ct];
      avv[rt][ct] = aacc[rt][ct] + dacc[rt][ct];
      short4v pk = { (short)f2bf(g[0]), (short)f2bf(g[1]),
                     (short)f2bf(g[2]), (short)f2bf(g[3]) };
      *(short4v*)(bufA + col*256 + SWZ(col, r0*2)) = pk;
    }
  }
  __syncthreads();

  // ---- g1 = relu(Wg1 @ gin + bg1) -> bufB (stride 256B) ----
  {
    f32x4 gacc[2][4];
#pragma unroll
    for (int rt = 0; rt < 2; ++rt) {
      const int r0 = rg*32 + rt*16 + kg*4;
      f32x4 bv = *(const f32x4*)(bg1 + r0);
#pragma unroll
      for (int ct = 0; ct < 4; ++ct) gacc[rt][ct] = bv;
    }
#pragma unroll
    for (int ks = 0; ks < 4; ++ks) {
      short8v a0 = *(const short8v*)(Wg1_bf + (rg*32 +      l15)*HD + ks*32 + kg*8);
      short8v a1 = *(const short8v*)(Wg1_bf + (rg*32 + 16 + l15)*HD + ks*32 + kg*8);
#pragma unroll
      for (int ct = 0; ct < 4; ++ct) {
        const int col = cg*64 + ct*16 + l15;
        short8v bf = *(const short8v*)(bufA + col*256 + SWZ(col, (ks*32+kg*8)*2));
        gacc[0][ct] = mm(a0, bf, gacc[0][ct]);
        gacc[1][ct] = mm(a1, bf, gacc[1][ct]);
      }
    }
    __syncthreads();   // all bufB (x-chunk) reads are long done; reuse as g1T
#pragma unroll
    for (int rt = 0; rt < 2; ++rt) {
      const int r0 = rg*32 + rt*16 + kg*4;
#pragma unroll
      for (int ct = 0; ct < 4; ++ct) {
        const int col = cg*64 + ct*16 + l15;
        short4v pk = { (short)f2bf(fmaxf(gacc[rt][ct][0],0.f)),
                       (short)f2bf(fmaxf(gacc[rt][ct][1],0.f)),
                       (short)f2bf(fmaxf(gacc[rt][ct][2],0.f)),
                       (short)f2bf(fmaxf(gacc[rt][ct][3],0.f)) };
        *(short4v*)(bufB + col*256 + SWZ(col, r0*2)) = pk;
      }
    }
  }
  __syncthreads();

  // ---- g2 GEMM ----
  f32x4 g2acc[2][4];
#pragma unroll
  for (int rt = 0; rt < 2; ++rt) {
    const int r0 = rg*32 + rt*16 + kg*4;
    f32x4 bv = *(const f32x4*)(bg2 + r0);
#pragma unroll
    for (int ct = 0; ct < 4; ++ct) g2acc[rt][ct] = bv;
  }
#pragma unroll
  for (int ks = 0; ks < 4; ++ks) {
    short8v a0 = *(const short8v*)(Wg2_bf + (rg*32 +      l15)*HD + ks*32 + kg*8);
    short8v a1 = *(const short8v*)(Wg2_bf + (rg*32 + 16 + l15)*HD + ks*32 + kg*8);
#pragma unroll
    for (int ct = 0; ct < 4; ++ct) {
      const int col = cg*64 + ct*16 + l15;
      short8v bf = *(const short8v*)(bufB + col*256 + SWZ(col, (ks*32+kg*8)*2));
      g2acc[0][ct] = mm(a0, bf, g2acc[0][ct]);
      g2acc[1][ct] = mm(a1, bf, g2acc[1][ct]);
    }
  }

  // ---- softmax over s (16 lanes of a col-tile) + weighted sum -> y_ws ----
#pragma unroll
  for (int rt = 0; rt < 2; ++rt) {
#pragma unroll
    for (int ct = 0; ct < 4; ++ct) {
      f32x4 g = g2acc[rt][ct];
      f32x4 num, den;
#pragma unroll
      for (int j = 0; j < 4; ++j) {
        float mj = g[j];
        mj = fmaxf(mj, __shfl_xor(mj, 1));
        mj = fmaxf(mj, __shfl_xor(mj, 2));
        mj = fmaxf(mj, __shfl_xor(mj, 4));
        mj = fmaxf(mj, __shfl_xor(mj, 8));
        float e  = __expf(g[j] - mj);
        float n_ = e * avv[rt][ct][j], d_ = e;
        n_ += __shfl_xor(n_, 1); d_ += __shfl_xor(d_, 1);
        n_ += __shfl_xor(n_, 2); d_ += __shfl_xor(d_, 2);
        n_ += __shfl_xor(n_, 4); d_ += __shfl_xor(d_, 4);
        n_ += __shfl_xor(n_, 8); d_ += __shfl_xor(d_, 8);
        num[j] = n_; den[j] = d_;
      }
      const int p  = cg*4 + ct;
      const int r0 = rg*32 + rt*16 + kg*4;
      if (l15 < 4) {
        float n_ = (l15==0) ? num[0] : (l15==1) ? num[1] : (l15==2) ? num[2] : num[3];
        float d_ = (l15==0) ? den[0] : (l15==1) ? den[1] : (l15==2) ? den[2] : den[3];
        y_ws[((size_t)(b*NP) + n0 + p)*HD + r0 + l15] = n_ / d_;
      }
    }
  }
#undef XLOAD
#undef XWRITE
}

// ---------------------------------------------------------------------------
// Kernel 3 (unchanged fp32): out = W_down @ y + b_down + residual
// ---------------------------------------------------------------------------
__global__ __launch_bounds__(256) void k_down(
    const float* __restrict__ y_ws,
    const float* __restrict__ Wdown, const float* __restrict__ bdown,
    const float* __restrict__ xcent, float* __restrict__ out)
{
    __shared__ float yls[HD][SS];
    const int blk = blockIdx.x;
    const int b   = blk >> 8;
    const int n0  = (blk & 255) * SS;
    const int t   = threadIdx.x;

    {
        const float* src = y_ws + ((size_t)(b*NP + n0))*HD;
        float v[8];
        *(float4*)&v[0] = *(const float4*)(src + t*8);
        *(float4*)&v[4] = *(const float4*)(src + t*8 + 4);
#pragma unroll
        for (int j = 0; j < 8; ++j) {
            const int f = t*8 + j;
            yls[f & 127][f >> 7] = v[j];
        }
    }
    __syncthreads();

    const int c = t;
    float acc[SS];
    {
        const float bb = bdown[c];
#pragma unroll
        for (int p = 0; p < SS; ++p) acc[p] = bb;
    }
    const float* wr = Wdown + c*HD;
    for (int k4 = 0; k4 < HD/4; ++k4) {
        const float4 w4 = *(const float4*)&wr[k4*4];
        const float wv[4] = {w4.x, w4.y, w4.z, w4.w};
#pragma unroll
        for (int u = 0; u < 4; ++u) {
            const int k = k4*4 + u;
            float yr[SS];
            *(float4*)&yr[0]  = *(const float4*)&yls[k][0];
            *(float4*)&yr[4]  = *(const float4*)&yls[k][4];
            *(float4*)&yr[8]  = *(const float4*)&yls[k][8];
            *(float4*)&yr[12] = *(const float4*)&yls[k][12];
#pragma unroll
            for (int p = 0; p < SS; ++p) acc[p] += wv[u]*yr[p];
        }
    }
    const size_t ob = ((size_t)(b*CH + c))*NP + n0;
#pragma unroll
    for (int p4 = 0; p4 < 4; ++p4) {
        const float4 r = *(const float4*)&xcent[ob + p4*4];
        float4 o;
        o.x = acc[p4*4+0] + r.x;
        o.y = acc[p4*4+1] + r.y;
        o.z = acc[p4*4+2] + r.z;
        o.w = acc[p4*4+3] + r.w;
        *(float4*)&out[ob + p4*4] = o;
    }
}

// ---------------------------------------------------------------------------
extern "C" void kernel_launch(void* const* d_in, const int* in_sizes, int n_in,
                              void* d_out, int out_size, void* d_ws, size_t ws_size,
                              hipStream_t stream)
{
    const float* pcent  = (const float*)d_in[0];
    const float* xcent  = (const float*)d_in[1];
    const float* pfull  = (const float*)d_in[2];
    const float* xfull  = (const float*)d_in[3];
    const float* Wtop   = (const float*)d_in[4];
    const float* btop   = (const float*)d_in[5];
    const float* Wdown  = (const float*)d_in[6];
    const float* bdown  = (const float*)d_in[7];
    const float* Wphi   = (const float*)d_in[8];
    const float* bphi   = (const float*)d_in[9];
    const float* Wpsi   = (const float*)d_in[10];
    const float* bpsi   = (const float*)d_in[11];
    const float* Walpha = (const float*)d_in[12];
    const float* balpha = (const float*)d_in[13];
    const float* Wg1    = (const float*)d_in[14];
    const float* bg1    = (const float*)d_in[15];
    const float* Wg2    = (const float*)d_in[16];
    const float* bg2    = (const float*)d_in[17];
    const float* Wd1    = (const float*)d_in[18];
    const float* bd1    = (const float*)d_in[19];
    const float* Wd2    = (const float*)d_in[20];
    const float* bd2    = (const float*)d_in[21];
    float* out = (float*)d_out;

    float* phi_ws = (float*)d_ws;                         // 8.4 MB
    float* y_ws   = phi_ws + (size_t)BDIM*NP*HD;          // 8.4 MB
    short* Wpsi_bf   = (short*)(y_ws + (size_t)BDIM*NP*HD);
    short* Walpha_bf = Wpsi_bf   + HD*CH;
    short* Wd2_bf    = Walpha_bf + HD*CH;
    short* Wg1_bf    = Wd2_bf    + HD*HD;
    short* Wg2_bf    = Wg1_bf    + HD*HD;

    k_cvt<<<(HD*CH+255)/256, 256, 0, stream>>>(Wpsi,   Wpsi_bf,   HD*CH);
    k_cvt<<<(HD*CH+255)/256, 256, 0, stream>>>(Walpha, Walpha_bf, HD*CH);
    k_cvt<<<(HD*HD+255)/256, 256, 0, stream>>>(Wd2,    Wd2_bf,    HD*HD);
    k_cvt<<<(HD*HD+255)/256, 256, 0, stream>>>(Wg1,    Wg1_bf,    HD*HD);
    k_cvt<<<(HD*HD+255)/256, 256, 0, stream>>>(Wg2,    Wg2_bf,    HD*HD);

    k_phi<<<BDIM*NP/SS, 256, 0, stream>>>(xcent, Wtop, btop, Wphi, bphi, phi_ws);
    k_main_mfma<<<BDIM*NP/PB, 512, 0, stream>>>(pcent, pfull, xfull,
                                                Wpsi_bf, bpsi, Walpha_bf, balpha,
                                                Wd2_bf, bd2, Wg1_bf, bg1, Wg2_bf, bg2,
                                                Wd1, bd1, phi_ws, y_ws);
    k_down<<<BDIM*NP/SS, 256, 0, stream>>>(y_ws, Wdown, bdown, xcent, out);
}

// Round 4
// 532.823 us; speedup vs baseline: 4.2449x; 1.2972x over previous
//
#include <hip/hip_runtime.h>
#include <cstddef>

#define BDIM 4
#define CH   256
#define HD   128
#define NP   4096
#define SS   16
#define PB   4       // points per k_main block
#define NCOL 64      // PB*SS GEMM columns

typedef __attribute__((ext_vector_type(8))) short short8v;
typedef __attribute__((ext_vector_type(4))) short short4v;
typedef __attribute__((ext_vector_type(4))) float f32x4;

// XOR swizzle (bit 4) on byte offset within a K-contiguous LDS row.
#define SWZ(col, off) ((off) ^ (((col)&7)<<4))

__device__ __forceinline__ unsigned short f2bf(float f){
  union { float f; unsigned u; } v; v.f = f;
  return (unsigned short)((v.u + 0x7fffu + ((v.u>>16)&1u)) >> 16);  // RNE
}
__device__ __forceinline__ float bf2f(unsigned short s){
  union { unsigned u; float f; } v; v.u = ((unsigned)s) << 16; return v.f;
}
__device__ __forceinline__ f32x4 mm(short8v a, short8v b, f32x4 c){
  return __builtin_amdgcn_mfma_f32_16x16x32_bf16(a, b, c, 0, 0, 0);
}

// Fragment-ordered weight layout for A-operands:
//   frag[(rb*(K/32)+ks)*64 + lane][8]  with row = rb*16+(lane&15), k = ks*32+(lane>>4)*8+i
// -> A-frag load = lane-coalesced dwordx4 (1 KB/wave/instr), no gathers.

// frag offsets (in shorts) within the frag pool:
#define FO_COMB   0        // [128,256]
#define FO_PSI    32768    // [128,256]
#define FO_ALPHA  65536    // [128,256]
#define FO_D2     98304    // [128,128]
#define FO_G1     114688   // [128,128]
#define FO_G2     131072   // [128,128]
#define FO_DOWN   147456   // [256,128]
#define FRAG_TOT  180224

// ---------------------------------------------------------------------------
// prep1: Wcomb = Wphi @ Wtop (fp32), bcomb = Wphi @ btop + bphi
// ---------------------------------------------------------------------------
__global__ __launch_bounds__(256) void k_prep1(
    const float* __restrict__ Wphi, const float* __restrict__ Wtop,
    const float* __restrict__ bphi, const float* __restrict__ btop,
    float* __restrict__ Wcomb, float* __restrict__ bcomb)
{
  __shared__ float wrow[HD];
  __shared__ float bpart[HD];
  const int o = blockIdx.x;      // 0..127
  const int t = threadIdx.x;     // 0..255  (= output column c)
  if (t < HD) { wrow[t] = Wphi[o*HD + t]; bpart[t] = wrow[t] * btop[t]; }
  __syncthreads();
  float acc = 0.f;
  for (int h = 0; h < HD; ++h) acc += wrow[h] * Wtop[h*CH + t];
  Wcomb[o*CH + t] = acc;
  if (t == 0) {
    float s = bphi[o];
    for (int h = 0; h < HD; ++h) s += bpart[h];
    bcomb[o] = s;
  }
}

// ---------------------------------------------------------------------------
// prep2: convert 7 matrices to bf16 fragment order. 352 blocks x 64 threads.
// ---------------------------------------------------------------------------
__global__ __launch_bounds__(64) void k_prep2(
    const float* __restrict__ Wcomb, const float* __restrict__ Wpsi,
    const float* __restrict__ Walpha, const float* __restrict__ Wd2,
    const float* __restrict__ Wg1, const float* __restrict__ Wg2,
    const float* __restrict__ Wdown, short* __restrict__ frags)
{
  const int fb = blockIdx.x, lane = threadIdx.x;
  const float* src; int K, loc, off;
  if      (fb <  64) { src = Wcomb;  K = 256; loc = fb;       off = FO_COMB;  }
  else if (fb < 128) { src = Wpsi;   K = 256; loc = fb - 64;  off = FO_PSI;   }
  else if (fb < 192) { src = Walpha; K = 256; loc = fb - 128; off = FO_ALPHA; }
  else if (fb < 224) { src = Wd2;    K = 128; loc = fb - 192; off = FO_D2;    }
  else if (fb < 256) { src = Wg1;    K = 128; loc = fb - 224; off = FO_G1;    }
  else if (fb < 288) { src = Wg2;    K = 128; loc = fb - 256; off = FO_G2;    }
  else               { src = Wdown;  K = 128; loc = fb - 288; off = FO_DOWN;  }
  const int nks = K >> 5;
  const int rb = loc / nks, ks = loc % nks;
  const float* s = src + (size_t)(rb*16 + (lane&15))*K + ks*32 + (lane>>4)*8;
  short8v pk;
#pragma unroll
  for (int i = 0; i < 8; ++i) pk[i] = (short)f2bf(s[i]);
  *(short8v*)(frags + off + ((size_t)loc*64 + lane)*8) = pk;
}

// ---------------------------------------------------------------------------
// k_phi: phi = Wcomb @ x_centroids + bcomb  (bf16 MFMA, 64 points/block)
// ---------------------------------------------------------------------------
__global__ __launch_bounds__(512) void k_phi(
    const float* __restrict__ xcent, const short* __restrict__ frags,
    const float* __restrict__ bcomb, short* __restrict__ phi_bf)
{
  __shared__ __align__(16) char bufX[64*512];  // [64 col][256 k] bf16, stride 512B
  const int blk = blockIdx.x;          // 256 blocks
  const int b   = blk >> 6;
  const int n0  = (blk & 63) * 64;
  const int t   = threadIdx.x;
  const int w   = t >> 6, lane = t & 63;
  const int rg  = w & 3, cg = w >> 2;
  const int l15 = lane & 15, kg = lane >> 4;

  {  // stage x_centroids^T -> bufX (transpose via scalar b16 writes)
    const int c = t >> 1, half = t & 1;
    const float* src = xcent + ((size_t)(b*CH + c))*NP + n0 + half*32;
#pragma unroll
    for (int q = 0; q < 8; ++q) {
      const float4 v = *(const float4*)(src + q*4);
      const float vv[4] = {v.x, v.y, v.z, v.w};
#pragma unroll
      for (int u = 0; u < 4; ++u) {
        const int col = half*32 + q*4 + u;
        *(short*)(bufX + col*512 + SWZ(col, c*2)) = (short)f2bf(vv[u]);
      }
    }
  }
  __syncthreads();

  f32x4 acc[2][2];
#pragma unroll
  for (int rt = 0; rt < 2; ++rt) {
    const int r0 = rg*32 + rt*16 + kg*4;
    f32x4 bv = *(const f32x4*)(bcomb + r0);
#pragma unroll
    for (int ct = 0; ct < 2; ++ct) acc[rt][ct] = bv;
  }
#pragma unroll
  for (int ks = 0; ks < 8; ++ks) {
    short8v a0 = *(const short8v*)(frags + FO_COMB + ((size_t)((rg*2+0)*8 + ks)*64 + lane)*8);
    short8v a1 = *(const short8v*)(frags + FO_COMB + ((size_t)((rg*2+1)*8 + ks)*64 + lane)*8);
#pragma unroll
    for (int ct = 0; ct < 2; ++ct) {
      const int col = cg*32 + ct*16 + l15;
      short8v bf = *(const short8v*)(bufX + col*512 + SWZ(col, (ks*32 + kg*8)*2));
      acc[0][ct] = mm(a0, bf, acc[0][ct]);
      acc[1][ct] = mm(a1, bf, acc[1][ct]);
    }
  }
  // store phi bf16: [pt][h]
#pragma unroll
  for (int rt = 0; rt < 2; ++rt)
#pragma unroll
    for (int ct = 0; ct < 2; ++ct) {
      const int pt = cg*32 + ct*16 + l15;
      const int r0 = rg*32 + rt*16 + kg*4;
      short* dst = phi_bf + ((size_t)(b*NP) + n0 + pt)*HD + r0;
#pragma unroll
      for (int j = 0; j < 4; ++j) dst[j] = (short)f2bf(acc[rt][ct][j]);
    }
}

// ---------------------------------------------------------------------------
// k_main: fused delta/psi/alpha/gamma/softmax. 4 points per block, 256 thr
// (4 waves: rg = wave = row group; each wave covers all 64 cols).
// LDS pool 34 KB. No min-waves cap: let the allocator pick VGPRs (no spills).
// ---------------------------------------------------------------------------
__global__ __launch_bounds__(256) void k_main(
    const float* __restrict__ pcent, const float* __restrict__ pfull,
    const float* __restrict__ xfull, const short* __restrict__ frags,
    const float* __restrict__ bpsi, const float* __restrict__ balpha,
    const float* __restrict__ bd2,  const float* __restrict__ bg1,
    const float* __restrict__ bg2,
    const float* __restrict__ Wd1,  const float* __restrict__ bd1,
    const short* __restrict__ phi_bf, short* __restrict__ y_bf)
{
  __shared__ __align__(16) char pool[34816];
  char* bufA = pool;                      // [64 col][128 k] bf16, stride 256B (d1T, later ginT)
  char* bufB = pool + 16384;              // 2 x 8 KB x-chunks [64 col][64 k] stride 128B; later g1T stride 256B
  float* phis = (float*)(pool + 32768);   // [4 pt][128 h] f32
  float* pipj = (float*)(pool + 16384);   // [3][64] staged early inside bufB slot0

  const int blk = blockIdx.x;             // 4096
  const int b   = blk >> 10;
  const int n0  = (blk & 1023) * PB;
  const int t   = threadIdx.x;
  const int w   = t >> 6, lane = t & 63;
  const int rg  = w;                      // rows rg*32..+31
  const int l15 = lane & 15, kg = lane >> 4;

  // ---- P0: stage pipj + phi ----
  if (t < 3*NCOL) {
    const int m = t >> 6, col = t & 63;
    const size_t ip = ((size_t)(b*3 + m))*NP + n0;
    pipj[m*NCOL + col] = pcent[ip + (col>>4)] - pfull[ip*SS + col];
  }
  {
    const unsigned v = ((const unsigned*)(phi_bf + ((size_t)(b*NP) + n0)*HD))[t];
    phis[t*2]   = bf2f((unsigned short)(v & 0xffff));
    phis[t*2+1] = bf2f((unsigned short)(v >> 16));
  }
  __syncthreads();

  // x staging macros (single reg set; XWRITE always precedes the next XLOAD)
  float xl[16];
  const float* xsrc = xfull + ((size_t)(b*CH)*NP + n0)*SS;
#define XLOAD(cc) {                                                         \
  _Pragma("unroll") for (int j = 0; j < 16; ++j)                            \
    xl[j] = xsrc[(size_t)((cc)*64 + w*16 + j)*(NP*SS) + lane]; }
#define XWRITE(cc) {                                                        \
  char* cb = bufB + ((cc)&1)*8192;                                          \
  short8v p0_, p1_;                                                         \
  _Pragma("unroll") for (int j = 0; j < 8; ++j) {                           \
    p0_[j] = (short)f2bf(xl[j]); p1_[j] = (short)f2bf(xl[8+j]); }           \
  *(short8v*)(cb + lane*128 + SWZ(lane, w*32))      = p0_;                  \
  *(short8v*)(cb + lane*128 + SWZ(lane, w*32 + 16)) = p1_; }

  // ---- P1: issue chunk0 loads; d1 = relu(Wd1 @ pipj + bd1) -> bufA ----
  XLOAD(0);
  {
    const int col = t & 63;
    const int hq  = t >> 6;              // wave-uniform -> scalar weight loads
    const float q0 = pipj[0*NCOL+col], q1 = pipj[1*NCOL+col], q2 = pipj[2*NCOL+col];
#pragma unroll
    for (int i = 0; i < 4; ++i) {
      const int h0 = hq*32 + i*8;
      short8v pk;
#pragma unroll
      for (int j = 0; j < 8; ++j) {
        const int h = h0 + j;
        float v = bd1[h] + Wd1[h*3]*q0 + Wd1[h*3+1]*q1 + Wd1[h*3+2]*q2;
        pk[j] = (short)f2bf(fmaxf(v, 0.f));
      }
      *(short8v*)(bufA + col*256 + SWZ(col, h0*2)) = pk;
    }
  }
  __syncthreads();

  // ---- P2: XWRITE(0) (pipj dead past barrier); delta GEMM (K=128, bufA) ----
  f32x4 dacc[2][4];
#pragma unroll
  for (int rt = 0; rt < 2; ++rt) {
    f32x4 bv = *(const f32x4*)(bd2 + rg*32 + rt*16 + kg*4);
#pragma unroll
    for (int ct = 0; ct < 4; ++ct) dacc[rt][ct] = bv;
  }
  XWRITE(0);
#pragma unroll
  for (int ks = 0; ks < 4; ++ks) {
    short8v a0 = *(const short8v*)(frags + FO_D2 + ((size_t)((rg*2+0)*4 + ks)*64 + lane)*8);
    short8v a1 = *(const short8v*)(frags + FO_D2 + ((size_t)((rg*2+1)*4 + ks)*64 + lane)*8);
#pragma unroll
    for (int ct = 0; ct < 4; ++ct) {
      const int col = ct*16 + l15;
      short8v bf = *(const short8v*)(bufA + col*256 + SWZ(col, (ks*32 + kg*8)*2));
      dacc[0][ct] = mm(a0, bf, dacc[0][ct]);
      dacc[1][ct] = mm(a1, bf, dacc[1][ct]);
    }
  }
  __syncthreads();

  // ---- P3..P6: psi & alpha GEMMs over 4 x-chunks (K=256), R2-proven schedule:
  //      XLOAD(cc+1) -> MFMA(chunk cc) -> XWRITE(cc+1) -> barrier ----
  f32x4 pacc[2][4], aacc[2][4];
#pragma unroll
  for (int rt = 0; rt < 2; ++rt) {
    f32x4 bp = *(const f32x4*)(bpsi   + rg*32 + rt*16 + kg*4);
    f32x4 ba = *(const f32x4*)(balpha + rg*32 + rt*16 + kg*4);
#pragma unroll
    for (int ct = 0; ct < 4; ++ct) { pacc[rt][ct] = bp; aacc[rt][ct] = ba; }
  }
#pragma unroll
  for (int cc = 0; cc < 4; ++cc) {
    if (cc < 3) XLOAD(cc+1);
    const char* cb = bufB + (cc&1)*8192;
    __builtin_amdgcn_s_setprio(1);
#pragma unroll
    for (int ks2 = 0; ks2 < 2; ++ks2) {
      const int ks = cc*2 + ks2;
      short8v ap0 = *(const short8v*)(frags + FO_PSI   + ((size_t)((rg*2+0)*8 + ks)*64 + lane)*8);
      short8v ap1 = *(const short8v*)(frags + FO_PSI   + ((size_t)((rg*2+1)*8 + ks)*64 + lane)*8);
      short8v aa0 = *(const short8v*)(frags + FO_ALPHA + ((size_t)((rg*2+0)*8 + ks)*64 + lane)*8);
      short8v aa1 = *(const short8v*)(frags + FO_ALPHA + ((size_t)((rg*2+1)*8 + ks)*64 + lane)*8);
#pragma unroll
      for (int ct = 0; ct < 4; ++ct) {
        const int col = ct*16 + l15;
        short8v bf = *(const short8v*)(cb + col*128 + SWZ(col, (ks2*32 + kg*8)*2));
        pacc[0][ct] = mm(ap0, bf, pacc[0][ct]);
        pacc[1][ct] = mm(ap1, bf, pacc[1][ct]);
        aacc[0][ct] = mm(aa0, bf, aacc[0][ct]);
        aacc[1][ct] = mm(aa1, bf, aacc[1][ct]);
      }
    }
    __builtin_amdgcn_s_setprio(0);
    if (cc < 3) XWRITE(cc+1);
    __syncthreads();
  }

  // ---- gin = phi - psi + delta -> bufA ; av = alpha + delta (regs) ----
  f32x4 avv[2][4];
#pragma unroll
  for (int rt = 0; rt < 2; ++rt) {
    const int r0 = rg*32 + rt*16 + kg*4;
#pragma unroll
    for (int ct = 0; ct < 4; ++ct) {
      const int col = ct*16 + l15;
      f32x4 ph = *(const f32x4*)(phis + ct*HD + r0);
      f32x4 g  = ph - pacc[rt][ct] + dacc[rt][ct];
      avv[rt][ct] = aacc[rt][ct] + dacc[rt][ct];
      short4v pk = { (short)f2bf(g[0]), (short)f2bf(g[1]),
                     (short)f2bf(g[2]), (short)f2bf(g[3]) };
      *(short4v*)(bufA + col*256 + SWZ(col, r0*2)) = pk;
    }
  }
  __syncthreads();

  // ---- g1 = relu(Wg1 @ gin + bg1) -> bufB (stride 256B) ----
  {
    f32x4 gacc[2][4];
#pragma unroll
    for (int rt = 0; rt < 2; ++rt) {
      f32x4 bv = *(const f32x4*)(bg1 + rg*32 + rt*16 + kg*4);
#pragma unroll
      for (int ct = 0; ct < 4; ++ct) gacc[rt][ct] = bv;
    }
#pragma unroll
    for (int ks = 0; ks < 4; ++ks) {
      short8v a0 = *(const short8v*)(frags + FO_G1 + ((size_t)((rg*2+0)*4 + ks)*64 + lane)*8);
      short8v a1 = *(const short8v*)(frags + FO_G1 + ((size_t)((rg*2+1)*4 + ks)*64 + lane)*8);
#pragma unroll
      for (int ct = 0; ct < 4; ++ct) {
        const int col = ct*16 + l15;
        short8v bf = *(const short8v*)(bufA + col*256 + SWZ(col, (ks*32 + kg*8)*2));
        gacc[0][ct] = mm(a0, bf, gacc[0][ct]);
        gacc[1][ct] = mm(a1, bf, gacc[1][ct]);
      }
    }
#pragma unroll
    for (int rt = 0; rt < 2; ++rt) {
      const int r0 = rg*32 + rt*16 + kg*4;
#pragma unroll
      for (int ct = 0; ct < 4; ++ct) {
        const int col = ct*16 + l15;
        short4v pk = { (short)f2bf(fmaxf(gacc[rt][ct][0],0.f)),
                       (short)f2bf(fmaxf(gacc[rt][ct][1],0.f)),
                       (short)f2bf(fmaxf(gacc[rt][ct][2],0.f)),
                       (short)f2bf(fmaxf(gacc[rt][ct][3],0.f)) };
        *(short4v*)(bufB + col*256 + SWZ(col, r0*2)) = pk;
      }
    }
  }
  __syncthreads();

  // ---- g2 GEMM ----
  f32x4 g2acc[2][4];
#pragma unroll
  for (int rt = 0; rt < 2; ++rt) {
    f32x4 bv = *(const f32x4*)(bg2 + rg*32 + rt*16 + kg*4);
#pragma unroll
    for (int ct = 0; ct < 4; ++ct) g2acc[rt][ct] = bv;
  }
#pragma unroll
  for (int ks = 0; ks < 4; ++ks) {
    short8v a0 = *(const short8v*)(frags + FO_G2 + ((size_t)((rg*2+0)*4 + ks)*64 + lane)*8);
    short8v a1 = *(const short8v*)(frags + FO_G2 + ((size_t)((rg*2+1)*4 + ks)*64 + lane)*8);
#pragma unroll
    for (int ct = 0; ct < 4; ++ct) {
      const int col = ct*16 + l15;
      short8v bf = *(const short8v*)(bufB + col*256 + SWZ(col, (ks*32 + kg*8)*2));
      g2acc[0][ct] = mm(a0, bf, g2acc[0][ct]);
      g2acc[1][ct] = mm(a1, bf, g2acc[1][ct]);
    }
  }

  // ---- softmax over s (16 lanes) + weighted sum -> y_bf ----
#pragma unroll
  for (int rt = 0; rt < 2; ++rt) {
#pragma unroll
    for (int ct = 0; ct < 4; ++ct) {
      f32x4 g = g2acc[rt][ct];
      f32x4 num, den;
#pragma unroll
      for (int j = 0; j < 4; ++j) {
        float mj = g[j];
        mj = fmaxf(mj, __shfl_xor(mj, 1));
        mj = fmaxf(mj, __shfl_xor(mj, 2));
        mj = fmaxf(mj, __shfl_xor(mj, 4));
        mj = fmaxf(mj, __shfl_xor(mj, 8));
        float e  = __expf(g[j] - mj);
        float n_ = e * avv[rt][ct][j], d_ = e;
        n_ += __shfl_xor(n_, 1); d_ += __shfl_xor(d_, 1);
        n_ += __shfl_xor(n_, 2); d_ += __shfl_xor(d_, 2);
        n_ += __shfl_xor(n_, 4); d_ += __shfl_xor(d_, 4);
        n_ += __shfl_xor(n_, 8); d_ += __shfl_xor(d_, 8);
        num[j] = n_; den[j] = d_;
      }
      const int r0 = rg*32 + rt*16 + kg*4;
      if (l15 < 4) {
        float n_ = (l15==0) ? num[0] : (l15==1) ? num[1] : (l15==2) ? num[2] : num[3];
        float d_ = (l15==0) ? den[0] : (l15==1) ? den[1] : (l15==2) ? den[2] : den[3];
        y_bf[((size_t)(b*NP) + n0 + ct)*HD + r0 + l15] = (short)f2bf(n_ / d_);
      }
    }
  }
#undef XLOAD
#undef XWRITE
}

// ---------------------------------------------------------------------------
// k_down: out = Wdown @ y + bdown + residual. 64 points/block, MFMA.
// ---------------------------------------------------------------------------
__global__ __launch_bounds__(512) void k_down(
    const short* __restrict__ y_bf, const short* __restrict__ frags,
    const float* __restrict__ bdown, const float* __restrict__ xcent,
    float* __restrict__ out)
{
  __shared__ __align__(16) char bufY[64*256];   // [64 col][128 k] bf16, stride 256B
  const int blk = blockIdx.x;        // 256
  const int b   = blk >> 6;
  const int n0  = (blk & 63) * 64;
  const int t   = threadIdx.x;
  const int w   = t >> 6, lane = t & 63;
  const int rg  = w & 3, cg = w >> 2;
  const int l15 = lane & 15, kg = lane >> 4;

  {  // stage y tile (contiguous 16B loads -> swizzled b128 writes)
    const int pt = t >> 3, h0 = (t & 7) * 16;
    const short* src = y_bf + ((size_t)(b*NP) + n0 + pt)*HD + h0;
    short8v v0 = *(const short8v*)(src);
    short8v v1 = *(const short8v*)(src + 8);
    *(short8v*)(bufY + pt*256 + SWZ(pt, h0*2))      = v0;
    *(short8v*)(bufY + pt*256 + SWZ(pt, h0*2 + 16)) = v1;
  }
  __syncthreads();

  f32x4 acc[4][2];
#pragma unroll
  for (int rt = 0; rt < 4; ++rt) {
    f32x4 bv = *(const f32x4*)(bdown + rg*64 + rt*16 + kg*4);
#pragma unroll
    for (int ct = 0; ct < 2; ++ct) acc[rt][ct] = bv;
  }
#pragma unroll
  for (int ks = 0; ks < 4; ++ks) {
    short8v a[4];
#pragma unroll
    for (int rt = 0; rt < 4; ++rt)
      a[rt] = *(const short8v*)(frags + FO_DOWN + ((size_t)((rg*4+rt)*4 + ks)*64 + lane)*8);
#pragma unroll
    for (int ct = 0; ct < 2; ++ct) {
      const int col = cg*32 + ct*16 + l15;
      short8v bf = *(const short8v*)(bufY + col*256 + SWZ(col, (ks*32 + kg*8)*2));
#pragma unroll
      for (int rt = 0; rt < 4; ++rt) acc[rt][ct] = mm(a[rt], bf, acc[rt][ct]);
    }
  }
  // epilogue: +residual (each instr: 4 x 64B contiguous segments)
#pragma unroll
  for (int rt = 0; rt < 4; ++rt)
#pragma unroll
    for (int ct = 0; ct < 2; ++ct) {
      const int col = cg*32 + ct*16 + l15;
#pragma unroll
      for (int j = 0; j < 4; ++j) {
        const int r = rg*64 + rt*16 + kg*4 + j;
        const size_t addr = ((size_t)(b*CH + r))*NP + n0 + col;
        out[addr] = acc[rt][ct][j] + xcent[addr];
      }
    }
}

// ---------------------------------------------------------------------------
extern "C" void kernel_launch(void* const* d_in, const int* in_sizes, int n_in,
                              void* d_out, int out_size, void* d_ws, size_t ws_size,
                              hipStream_t stream)
{
    const float* pcent  = (const float*)d_in[0];
    const float* xcent  = (const float*)d_in[1];
    const float* pfull  = (const float*)d_in[2];
    const float* xfull  = (const float*)d_in[3];
    const float* Wtop   = (const float*)d_in[4];
    const float* btop   = (const float*)d_in[5];
    const float* Wdown  = (const float*)d_in[6];
    const float* bdown  = (const float*)d_in[7];
    const float* Wphi   = (const float*)d_in[8];
    const float* bphi   = (const float*)d_in[9];
    const float* Wpsi   = (const float*)d_in[10];
    const float* bpsi   = (const float*)d_in[11];
    const float* Walpha = (const float*)d_in[12];
    const float* balpha = (const float*)d_in[13];
    const float* Wg1    = (const float*)d_in[14];
    const float* bg1    = (const float*)d_in[15];
    const float* Wg2    = (const float*)d_in[16];
    const float* bg2    = (const float*)d_in[17];
    const float* Wd1    = (const float*)d_in[18];
    const float* bd1    = (const float*)d_in[19];
    const float* Wd2    = (const float*)d_in[20];
    const float* bd2    = (const float*)d_in[21];
    float* out = (float*)d_out;

    float* Wcomb_f = (float*)d_ws;                       // 32768 f32
    float* bcomb   = Wcomb_f + 32768;                    // 128 f32
    short* frags   = (short*)(bcomb + 128);              // FRAG_TOT shorts
    short* phi_bf  = frags + FRAG_TOT;                   // B*N*H bf16 (4 MB)
    short* y_bf    = phi_bf + (size_t)BDIM*NP*HD;        // 4 MB

    k_prep1<<<HD, 256, 0, stream>>>(Wphi, Wtop, bphi, btop, Wcomb_f, bcomb);
    k_prep2<<<352, 64, 0, stream>>>(Wcomb_f, Wpsi, Walpha, Wd2, Wg1, Wg2, Wdown, frags);
    k_phi  <<<BDIM*NP/64, 512, 0, stream>>>(xcent, frags, bcomb, phi_bf);
    k_main <<<BDIM*NP/PB, 256, 0, stream>>>(pcent, pfull, xfull, frags,
                                            bpsi, balpha, bd2, bg1, bg2,
                                            Wd1, bd1, phi_bf, y_bf);
    k_down <<<BDIM*NP/64, 512, 0, stream>>>(y_bf, frags, bdown, xcent, out);
}